// Round 5
// baseline (432.575 us; speedup 1.0000x reference)
//
#include <hip/hip_runtime.h>

#define IMG_H 512
#define IMG_W 512
#define CH_STRIDE (IMG_H*IMG_W)     // 262144
#define IMG_STRIDE (3*CH_STRIDE)

using f4 = __attribute__((ext_vector_type(4))) float;
using h4 = __attribute__((ext_vector_type(4))) _Float16;
using h8 = __attribute__((ext_vector_type(8))) _Float16;

// acc: 64 slots x 32 floats (128 B apart):
// 0=con 1=gx 2=gy 3=cb 4=cr 5=ssim_rgb 6=ssim_ir
#define NSLOT 64
#define SLOT_F 32

__global__ __launch_bounds__(256) void k_zero(float* __restrict__ acc) {
  int i = threadIdx.x;
  *(f4*)&acc[i*8]     = f4{0,0,0,0};
  *(f4*)&acc[i*8 + 4] = f4{0,0,0,0};
}

__device__ __forceinline__ float block_sum(float v, float* red) {
  #pragma unroll
  for (int o = 32; o > 0; o >>= 1) v += __shfl_down(v, o, 64);
  __syncthreads();
  if ((threadIdx.x & 63) == 0) red[threadIdx.x >> 6] = v;
  __syncthreads();
  return red[0] + red[1] + red[2] + red[3];
}

// ---- sobel geometry: tile 64x16, halo 1; LDS row stride 68 floats -------
#define R1W 68
#define R1N (18*R1W)   // 1224 floats per field

// ---- ssim geometry (MFMA formulation) -----------------------------------
// F: 48 rows x 104-stride halves (96 cols; col u <-> image x = x0-8+u)
// H = F x Gx  (Gx[u][c] = g[u-c-3], band 0..10) -> H_T col-major in LDS
// Out = Gy x H (Gy[y][r] = g[r-y], band 0..10)
#define FST 104                 // F row stride (halves); 208 B: b128-friendly
#define FSZ (48*FST*2)          // 9984 B per field
#define HTST 72                 // H_T row stride (halves per col); 144 B
#define HTSZ (64*HTST*2)        // 9216 B per buffer
#define SMEM_BYTES (2*FSZ + 2*HTSZ)   // 38400

__global__ __launch_bounds__(256, 4) void k_main(
    const float* __restrict__ vis, const float* __restrict__ ir,
    const float* __restrict__ fuse, float* __restrict__ acc)
{
  __shared__ __align__(16) char smem[SMEM_BYTES];
  __shared__ float red[4];
  __shared__ float gtab[96];    // zero-padded gaussian band table, g at 40..50
  const int tid = threadIdx.x;
  const int bid = blockIdx.x;
  float* aslot = acc + (bid & (NSLOT-1))*SLOT_F;

  if (bid < 8192) {
    // ================= SSIM block (MFMA separable conv) =================
    const int z = bid >> 7;             // n*4 + pair
    const int n = z >> 2, pair = z & 3;
    const int x0 = (bid & 7)*64;
    const int y0 = ((bid >> 3) & 15)*32;
    _Float16* FX  = (_Float16*)smem;
    _Float16* FY  = (_Float16*)(smem + FSZ);
    _Float16* HT0 = (_Float16*)(smem + 2*FSZ);
    _Float16* HT1 = (_Float16*)(smem + 2*FSZ + HTSZ);

    // Gaussian weights (fp64-accurate unnormalized exp(-d^2/4.5), normalized)
    float g[11];
    {
      const float gu[6] = {0.00386592014f, 0.02856550078f, 0.13533528324f,
                           0.41111229050f, 0.80073740292f, 1.0f};
      float gs = 0.f;
      #pragma unroll
      for (int i = 0; i < 11; ++i) { g[i] = gu[i < 6 ? i : 10 - i]; gs += g[i]; }
      #pragma unroll
      for (int i = 0; i < 11; ++i) g[i] /= gs;
    }

    // ---- stage F (f16, zero-padded), 1152 tasks = 48 rows x 24 f4-groups
    if (pair < 3) {
      const float* xb = vis  + (n*3 + pair)*CH_STRIDE;
      const float* yb = fuse + (n*3 + pair)*CH_STRIDE;
      for (int i = tid; i < 1152; i += 256) {
        int row = i / 24, k = i - row*24;
        int gy = y0 - 5 + row, gx = x0 - 8 + 4*k;
        f4 xv = {0,0,0,0}, yv = {0,0,0,0};
        if ((unsigned)gy < IMG_H && (unsigned)gx < IMG_W) {
          int off = gy*IMG_W + gx;
          xv = *(const f4*)&xb[off];
          yv = *(const f4*)&yb[off];
        }
        int ib = row*FST + 4*k;
        *(h4*)&FX[ib] = h4{(_Float16)xv.x,(_Float16)xv.y,(_Float16)xv.z,(_Float16)xv.w};
        *(h4*)&FY[ib] = h4{(_Float16)yv.x,(_Float16)yv.y,(_Float16)yv.z,(_Float16)yv.w};
      }
    } else {
      const float* xb = ir   + n*IMG_STRIDE;
      const float* fb = fuse + n*IMG_STRIDE;
      for (int i = tid; i < 1152; i += 256) {
        int row = i / 24, k = i - row*24;
        int gy = y0 - 5 + row, gx = x0 - 8 + 4*k;
        f4 xv = {0,0,0,0}, yv = {0,0,0,0};
        if ((unsigned)gy < IMG_H && (unsigned)gx < IMG_W) {
          int off = gy*IMG_W + gx;
          xv = *(const f4*)&xb[off];
          f4 rr = *(const f4*)&fb[off];
          f4 gg = *(const f4*)&fb[off + CH_STRIDE];
          f4 bb = *(const f4*)&fb[off + 2*CH_STRIDE];
          #pragma unroll
          for (int j = 0; j < 4; ++j)
            yv[j] = 0.2989f*rr[j] + 0.587f*gg[j] + 0.114f*bb[j];
        }
        int ib = row*FST + 4*k;
        *(h4*)&FX[ib] = h4{(_Float16)xv.x,(_Float16)xv.y,(_Float16)xv.z,(_Float16)xv.w};
        *(h4*)&FY[ib] = h4{(_Float16)yv.x,(_Float16)yv.y,(_Float16)yv.z,(_Float16)yv.w};
      }
    }
    // band table
    if (tid < 96) gtab[tid] = 0.f;
    #pragma unroll
    for (int k = 0; k < 11; ++k) if (tid == 40 + k) gtab[40 + k] = g[k];
    // zero H_T rows 48..63 (never written by stage1; poison would NaN MFMA)
    for (int i = tid; i < 512; i += 256) {
      _Float16* HT = (i < 256) ? HT0 : HT1;
      int r2 = i & 255;
      int c = r2 >> 2, rseg = 48 + (r2 & 3)*4;
      *(h4*)&HT[c*HTST + rseg] = h4{(_Float16)0.f,(_Float16)0.f,(_Float16)0.f,(_Float16)0.f};
    }
    __syncthreads();

    const int w  = tid >> 6;
    const int l  = tid & 63;
    const int q  = l >> 4;
    const int li = l & 15;

    // stage1 B-fragments (Gx, banded): contributing K-steps per wave
    const int Kbase = w >> 1;
    const int nK = 1 + (w & 1);
    h8 gxf[2];
    #pragma unroll
    for (int kk = 0; kk < 2; ++kk) {
      h8 t = {0,0,0,0,0,0,0,0};
      if (kk < nK) {
        int idx0 = 40 + (Kbase + kk)*32 + q*8 - w*16 - li - 3;
        #pragma unroll
        for (int j = 0; j < 8; ++j) t[j] = (_Float16)gtab[idx0 + j];
      }
      gxf[kk] = t;
    }
    // stage2 A-fragments (Gy): contributing (M,K) = (0,0),(1,0),(1,1)
    h8 gyA[3];
    {
      const int MK[3][2] = {{0,0},{1,0},{1,1}};
      #pragma unroll
      for (int p = 0; p < 3; ++p) {
        int idx0 = 40 + MK[p][1]*32 + q*8 - MK[p][0]*16 - li;
        h8 t;
        #pragma unroll
        for (int j = 0; j < 8; ++j) t[j] = (_Float16)gtab[idx0 + j];
        gyA[p] = t;
      }
    }

    f4 accF[4][2];   // field (mu1,mu2,sP,sQ) x Mtile
    #pragma unroll
    for (int f = 0; f < 4; ++f)
      #pragma unroll
      for (int m = 0; m < 2; ++m) accF[f][m] = f4{0,0,0,0};

    const int cw = w*16 + li;           // this lane's output column (x-offset)

    for (int grp = 0; grp < 2; ++grp) {
      if (grp) __syncthreads();         // WAR before overwriting H_T
      // ---- stage 1: H = F x Gx for 2 fields of this group ----
      #pragma unroll
      for (int M = 0; M < 3; ++M) {
        f4 c0 = {0,0,0,0}, c1 = {0,0,0,0};
        for (int kk = 0; kk < nK; ++kk) {
          int K = Kbase + kk;
          int fo = (M*16 + li)*FST + K*32 + q*8;
          h8 ax = *(const h8*)(FX + fo);
          h8 ay = *(const h8*)(FY + fo);
          if (grp == 0) {
            c0 = __builtin_amdgcn_mfma_f32_16x16x32_f16(ax, gxf[kk], c0, 0, 0, 0);
            c1 = __builtin_amdgcn_mfma_f32_16x16x32_f16(ay, gxf[kk], c1, 0, 0, 0);
          } else {
            h8 ap = ax*ax + ay*ay;
            h8 aq = ax*ay;
            c0 = __builtin_amdgcn_mfma_f32_16x16x32_f16(ap, gxf[kk], c0, 0, 0, 0);
            c1 = __builtin_amdgcn_mfma_f32_16x16x32_f16(aq, gxf[kk], c1, 0, 0, 0);
          }
        }
        int ho = cw*HTST + M*16 + q*4;
        *(h4*)(HT0 + ho) = h4{(_Float16)c0.x,(_Float16)c0.y,(_Float16)c0.z,(_Float16)c0.w};
        *(h4*)(HT1 + ho) = h4{(_Float16)c1.x,(_Float16)c1.y,(_Float16)c1.z,(_Float16)c1.w};
      }
      __syncthreads();
      // ---- stage 2: Out = Gy x H for the 2 fields ----
      #pragma unroll
      for (int f = 0; f < 2; ++f) {
        const _Float16* HT = f ? HT1 : HT0;
        int fi = grp*2 + f;
        h8 b0 = *(const h8*)(HT + cw*HTST + q*8);
        accF[fi][0] = __builtin_amdgcn_mfma_f32_16x16x32_f16(gyA[0], b0, accF[fi][0], 0, 0, 0);
        accF[fi][1] = __builtin_amdgcn_mfma_f32_16x16x32_f16(gyA[1], b0, accF[fi][1], 0, 0, 0);
        h8 b1 = *(const h8*)(HT + cw*HTST + 32 + q*8);
        accF[fi][1] = __builtin_amdgcn_mfma_f32_16x16x32_f16(gyA[2], b1, accF[fi][1], 0, 0, 0);
      }
    }

    // ---- epilogue: SSIM per pixel (8 px per lane) ----
    float ss = 0.f;
    #pragma unroll
    for (int M = 0; M < 2; ++M) {
      #pragma unroll
      for (int r = 0; r < 4; ++r) {
        float mu1 = accF[0][M][r], mu2 = accF[1][M][r];
        float sP  = accF[2][M][r], sQ  = accF[3][M][r];
        float mu12 = mu1*mu2, mss = mu1*mu1 + mu2*mu2;
        float s12 = sQ - mu12, sps = sP - mss;
        ss += ((2.f*mu12 + 1e-4f)*(2.f*s12 + 9e-4f)) /
              ((mss + 1e-4f)*(sps + 9e-4f));
      }
    }
    float tot = block_sum(ss, red);
    if (tid == 0) atomicAdd(&aslot[(pair == 3) ? 6 : 5], tot);

  } else {
    // ================= point + sobel + color block =================
    const int r = bid - 8192;
    const int x0 = (r & 7)*64;
    const int y0 = ((r >> 3) & 31)*16;
    const int n  = r >> 8;
    float* s = (float*)smem;   // 3 fields x 1224 floats (14.7 KB)
    const int ox = (tid & 15)*4;
    const int oy = tid >> 4;

    float con=0.f, gxs=0.f, gys=0.f, cbs=0.f, crs=0.f;
    float pv[3][4], pf[3][4];

    for (int c = 0; c < 3; ++c) {
      const float* pv0 = vis  + (n*3 + c)*CH_STRIDE;
      const float* pi0 = ir   + (n*3 + c)*CH_STRIDE;
      const float* pf0 = fuse + (n*3 + c)*CH_STRIDE;
      // interior: 3 fields x 18 rows x 16 f4 = 864 groups
      for (int i = tid; i < 864; i += 256) {
        int f = i / 288;
        int rr = i - f*288;
        int row = rr >> 4, k = rr & 15;
        int gy = y0 - 1 + row, gx = x0 + 4*k;
        f4 v = {0,0,0,0};
        const float* bp = (f == 0) ? pv0 : ((f == 1) ? pi0 : pf0);
        if ((unsigned)gy < IMG_H) v = *(const f4*)&bp[gy*IMG_W + gx];
        float* dst = s + f*R1N + row*R1W + 1 + 4*k;
        dst[0]=v.x; dst[1]=v.y; dst[2]=v.z; dst[3]=v.w;
      }
      // edges: 3 fields x 18 rows x 2 = 108 scalars
      if (tid < 108) {
        int f = tid / 36;
        int rr = tid - f*36;
        int row = rr >> 1, side = rr & 1;
        int gy = y0 - 1 + row;
        int gx = side ? (x0 + 64) : (x0 - 1);
        float v = 0.f;
        const float* bp = (f == 0) ? pv0 : ((f == 1) ? pi0 : pf0);
        if ((unsigned)gx < IMG_W && (unsigned)gy < IMG_H) v = bp[gy*IMG_W + gx];
        s[f*R1N + row*R1W + (side ? 65 : 0)] = v;
      }
      __syncthreads();

      float cen[3][4], gxv[3][4], gyv[3][4];
      #pragma unroll
      for (int t = 0; t < 3; ++t) {
        const float* sf = s + t*R1N;
        float r0[8], r1[8], r2[8];
        {
          f4 a = *(const f4*)&sf[(oy+0)*R1W + ox], b = *(const f4*)&sf[(oy+0)*R1W + ox + 4];
          r0[0]=a.x; r0[1]=a.y; r0[2]=a.z; r0[3]=a.w; r0[4]=b.x; r0[5]=b.y; r0[6]=b.z; r0[7]=b.w;
        }
        {
          f4 a = *(const f4*)&sf[(oy+1)*R1W + ox], b = *(const f4*)&sf[(oy+1)*R1W + ox + 4];
          r1[0]=a.x; r1[1]=a.y; r1[2]=a.z; r1[3]=a.w; r1[4]=b.x; r1[5]=b.y; r1[6]=b.z; r1[7]=b.w;
        }
        {
          f4 a = *(const f4*)&sf[(oy+2)*R1W + ox], b = *(const f4*)&sf[(oy+2)*R1W + ox + 4];
          r2[0]=a.x; r2[1]=a.y; r2[2]=a.z; r2[3]=a.w; r2[4]=b.x; r2[5]=b.y; r2[6]=b.z; r2[7]=b.w;
        }
        #pragma unroll
        for (int j = 0; j < 4; ++j) {
          gxv[t][j] = (r0[j+2]-r0[j]) + 2.f*(r1[j+2]-r1[j]) + (r2[j+2]-r2[j]);
          gyv[t][j] = (r0[j] + 2.f*r0[j+1] + r0[j+2]) - (r2[j] + 2.f*r2[j+1] + r2[j+2]);
          cen[t][j] = r1[j+1];
        }
      }
      #pragma unroll
      for (int j = 0; j < 4; ++j) {
        con += fabsf(cen[2][j] - fmaxf(cen[0][j], cen[1][j]));
        gxs += fabsf(gxv[2][j] - fmaxf(gxv[0][j], gxv[1][j]));
        gys += fabsf(gyv[2][j] - fmaxf(gyv[0][j], gyv[1][j]));
        pv[c][j] = cen[0][j];
        pf[c][j] = cen[2][j];
      }
      __syncthreads();   // WAR guard before restaging
    }

    #pragma unroll
    for (int j = 0; j < 4; ++j) {
      float Yf = 0.299f*pf[0][j] + 0.587f*pf[1][j] + 0.114f*pf[2][j];
      float Yv = 0.299f*pv[0][j] + 0.587f*pv[1][j] + 0.114f*pv[2][j];
      crs += fabsf(0.713f*((pf[0][j]-Yf) - (pv[0][j]-Yv)));
      cbs += fabsf(0.564f*((pf[2][j]-Yf) - (pv[2][j]-Yv)));
    }

    float r0 = block_sum(con, red);
    float r1 = block_sum(gxs, red);
    float r2 = block_sum(gys, red);
    float r3 = block_sum(cbs, red);
    float r4 = block_sum(crs, red);
    if (tid == 0) {
      atomicAdd(&aslot[0], r0);
      atomicAdd(&aslot[1], r1);
      atomicAdd(&aslot[2], r2);
      atomicAdd(&aslot[3], r3);
      atomicAdd(&aslot[4], r4);
    }
  }
}

// ---------------- final combine: one wave over 64 slots -------------------
__global__ __launch_bounds__(64) void k_final(
    const float* __restrict__ acc, float* __restrict__ out)
{
  int lane = threadIdx.x;
  float s[7];
  #pragma unroll
  for (int c = 0; c < 7; ++c) {
    float x = acc[lane*SLOT_F + c];
    #pragma unroll
    for (int o = 32; o > 0; o >>= 1) x += __shfl_down(x, o, 64);
    s[c] = x;
  }
  if (lane == 0) {
    const float N3 = 16.f*3.f*512.f*512.f;
    const float N1 = 16.f*512.f*512.f;
    float con_loss  = s[0] / N3;
    float grad_loss = 0.5f*(s[1]/N3) + 0.5f*(s[2]/N3);
    float color_loss = s[3]/N1 + s[4]/N1;
    float ssim_loss = 1.f - (s[5]/N3 + s[6]/N1)*0.5f;
    out[0] = 0.5f*con_loss + 0.2f*grad_loss + color_loss + 0.1f*ssim_loss;
  }
}

extern "C" void kernel_launch(void* const* d_in, const int* in_sizes, int n_in,
                              void* d_out, int out_size, void* d_ws, size_t ws_size,
                              hipStream_t stream) {
  (void)in_sizes; (void)n_in; (void)out_size; (void)ws_size;
  const float* vis  = (const float*)d_in[0];
  const float* ir   = (const float*)d_in[1];
  const float* fuse = (const float*)d_in[2];
  float* out = (float*)d_out;
  float* acc = (float*)d_ws;   // 64 slots x 32 floats = 8 KB

  k_zero<<<dim3(1,1,1), dim3(256,1,1), 0, stream>>>(acc);
  k_main<<<dim3(12288,1,1), dim3(256,1,1), 0, stream>>>(vis, ir, fuse, acc);
  k_final<<<dim3(1,1,1), dim3(64,1,1), 0, stream>>>(acc, out);
}

// Round 6
// 245.484 us; speedup vs baseline: 1.7621x; 1.7621x over previous
//
#include <hip/hip_runtime.h>

#define IMG_H 512
#define IMG_W 512
#define CH_STRIDE (IMG_H*IMG_W)     // 262144
#define IMG_STRIDE (3*CH_STRIDE)

using f4 = __attribute__((ext_vector_type(4))) float;
using h4 = __attribute__((ext_vector_type(4))) _Float16;
using h8 = __attribute__((ext_vector_type(8))) _Float16;

// acc: 64 slots x 32 floats (128 B apart):
// 0=con 1=gx 2=gy 3=cb 4=cr 5=ssim_rgb 6=ssim_ir
#define NSLOT 64
#define SLOT_F 32

__global__ __launch_bounds__(256) void k_zero(float* __restrict__ acc) {
  int i = threadIdx.x;
  *(f4*)&acc[i*8]     = f4{0,0,0,0};
  *(f4*)&acc[i*8 + 4] = f4{0,0,0,0};
}

__device__ __forceinline__ float block_sum(float v, float* red) {
  #pragma unroll
  for (int o = 32; o > 0; o >>= 1) v += __shfl_down(v, o, 64);
  __syncthreads();
  if ((threadIdx.x & 63) == 0) red[threadIdx.x >> 6] = v;
  __syncthreads();
  return red[0] + red[1] + red[2] + red[3];
}

__device__ __forceinline__ h8 splat8(_Float16 v) { return h8{v,v,v,v,v,v,v,v}; }

// ---- sobel geometry: tile 64x16, halo 1; LDS row stride 68 floats -------
#define R1W 68
#define R1N (18*R1W)   // 1224 floats per field

// ---- ssim geometry: tile 64x32, halo 5 ----------------------------------
// staged: 42 rows x 80 halves (col u <-> image x = x0-8+u)
// hbuf:   42 rows x 32 x-pairs, px-major interleave {A,B,P,Q}x2 = h8/pair
#define SXW 80
#define SXH 42
#define HB8 264                       // halves per hbuf row (32*8=256 +8 pad)
#define SSIM_SX_B (SXH*SXW*2)         // 6720
#define SSIM_HB_B (SXH*HB8*2)         // 22176
#define SMEM_BYTES (2*SSIM_SX_B + SSIM_HB_B)   // 35616 (sobel needs 14688)

__global__ __launch_bounds__(256, 4) void k_main(
    const float* __restrict__ vis, const float* __restrict__ ir,
    const float* __restrict__ fuse, float* __restrict__ acc)
{
  __shared__ __align__(16) char smem[SMEM_BYTES];
  __shared__ float red[4];
  const int tid = threadIdx.x;
  const int bid = blockIdx.x;
  float* aslot = acc + (bid & (NSLOT-1))*SLOT_F;

  if (bid < 8192) {
    // ================= SSIM block =================
    const int z = bid >> 7;             // n*4 + pair
    const int n = z >> 2, pair = z & 3;
    const int x0 = (bid & 7)*64;
    const int y0 = ((bid >> 3) & 15)*32;
    _Float16* sx = (_Float16*)smem;
    _Float16* sy = (_Float16*)(smem + SSIM_SX_B);
    _Float16* hb = (_Float16*)(smem + 2*SSIM_SX_B);

    // Gaussian weights (fp64-accurate unnormalized exp(-d^2/4.5), normalized)
    float g[11];
    _Float16 gh[11];
    {
      const float gu[6] = {0.00386592014f, 0.02856550078f, 0.13533528324f,
                           0.41111229050f, 0.80073740292f, 1.0f};
      float gs = 0.f;
      #pragma unroll
      for (int i = 0; i < 11; ++i) { g[i] = gu[i < 6 ? i : 10 - i]; gs += g[i]; }
      #pragma unroll
      for (int i = 0; i < 11; ++i) { g[i] /= gs; gh[i] = (_Float16)g[i]; }
    }

    // ---- stage (f16, zero-padded): 840 tasks = 42 rows x 20 f4-groups ---
    if (pair < 3) {
      const float* xb = vis  + (n*3 + pair)*CH_STRIDE;
      const float* yb = fuse + (n*3 + pair)*CH_STRIDE;
      for (int i = tid; i < SXH*20; i += 256) {
        int row = i / 20, k = i - row*20;
        int gy = y0 - 5 + row, gx = x0 - 8 + 4*k;
        f4 xv = {0,0,0,0}, yv = {0,0,0,0};
        if ((unsigned)gy < IMG_H && (unsigned)gx < IMG_W) {
          int off = gy*IMG_W + gx;
          xv = *(const f4*)&xb[off];
          yv = *(const f4*)&yb[off];
        }
        int ib = row*SXW + 4*k;
        *(h4*)&sx[ib] = h4{(_Float16)xv.x,(_Float16)xv.y,(_Float16)xv.z,(_Float16)xv.w};
        *(h4*)&sy[ib] = h4{(_Float16)yv.x,(_Float16)yv.y,(_Float16)yv.z,(_Float16)yv.w};
      }
    } else {
      const float* xb = ir   + n*IMG_STRIDE;
      const float* fb = fuse + n*IMG_STRIDE;
      for (int i = tid; i < SXH*20; i += 256) {
        int row = i / 20, k = i - row*20;
        int gy = y0 - 5 + row, gx = x0 - 8 + 4*k;
        f4 xv = {0,0,0,0}, yv = {0,0,0,0};
        if ((unsigned)gy < IMG_H && (unsigned)gx < IMG_W) {
          int off = gy*IMG_W + gx;
          xv = *(const f4*)&xb[off];
          f4 rr = *(const f4*)&fb[off];
          f4 gg = *(const f4*)&fb[off + CH_STRIDE];
          f4 bb = *(const f4*)&fb[off + 2*CH_STRIDE];
          #pragma unroll
          for (int j = 0; j < 4; ++j)
            yv[j] = 0.2989f*rr[j] + 0.587f*gg[j] + 0.114f*bb[j];
        }
        int ib = row*SXW + 4*k;
        *(h4*)&sx[ib] = h4{(_Float16)xv.x,(_Float16)xv.y,(_Float16)xv.z,(_Float16)xv.w};
        *(h4*)&sy[ib] = h4{(_Float16)yv.x,(_Float16)yv.y,(_Float16)yv.z,(_Float16)yv.w};
      }
    }
    __syncthreads();

    // ---- horizontal pass: 336 tasks = 42 rows x 8 x-groups (8-wide) -----
    for (int t = tid; t < SXH*8; t += 256) {
      int row = t >> 3, p0 = (t & 7)*4;        // pair base; x-offset = p0*2
      int base = row*SXW + p0*2;
      h8 xa0 = *(const h8*)&sx[base];
      h8 xa1 = *(const h8*)&sx[base+8];
      h8 xa2 = *(const h8*)&sx[base+16];
      h8 yb0 = *(const h8*)&sy[base];
      h8 yb1 = *(const h8*)&sy[base+8];
      h8 yb2 = *(const h8*)&sy[base+16];
      float wa[21], wb[21];
      #pragma unroll
      for (int u = 0; u < 21; ++u) {
        wa[u] = (float)(u < 8 ? xa0[u] : (u < 16 ? xa1[u-8] : xa2[u-16]));
        wb[u] = (float)(u < 8 ? yb0[u] : (u < 16 ? yb1[u-8] : yb2[u-16]));
      }
      h8 hA, hB, hP, hQ;
      {
        float a8[8] = {0,0,0,0,0,0,0,0};
        #pragma unroll
        for (int k = 0; k < 11; ++k) {
          float gk = g[k];
          #pragma unroll
          for (int j = 0; j < 8; ++j) a8[j] = fmaf(gk, wa[3+k+j], a8[j]);
        }
        #pragma unroll
        for (int j = 0; j < 8; ++j) hA[j] = (_Float16)a8[j];
      }
      {
        float b8[8] = {0,0,0,0,0,0,0,0};
        #pragma unroll
        for (int k = 0; k < 11; ++k) {
          float gk = g[k];
          #pragma unroll
          for (int j = 0; j < 8; ++j) b8[j] = fmaf(gk, wb[3+k+j], b8[j]);
        }
        #pragma unroll
        for (int j = 0; j < 8; ++j) hB[j] = (_Float16)b8[j];
      }
      {
        float wp[21];
        #pragma unroll
        for (int u = 3; u < 21; ++u) wp[u] = fmaf(wa[u], wa[u], wb[u]*wb[u]);
        float p8[8] = {0,0,0,0,0,0,0,0};
        #pragma unroll
        for (int k = 0; k < 11; ++k) {
          float gk = g[k];
          #pragma unroll
          for (int j = 0; j < 8; ++j) p8[j] = fmaf(gk, wp[3+k+j], p8[j]);
        }
        #pragma unroll
        for (int j = 0; j < 8; ++j) hP[j] = (_Float16)p8[j];
      }
      {
        float wq[21];
        #pragma unroll
        for (int u = 3; u < 21; ++u) wq[u] = wa[u]*wb[u];
        float q8[8] = {0,0,0,0,0,0,0,0};
        #pragma unroll
        for (int k = 0; k < 11; ++k) {
          float gk = g[k];
          #pragma unroll
          for (int j = 0; j < 8; ++j) q8[j] = fmaf(gk, wq[3+k+j], q8[j]);
        }
        #pragma unroll
        for (int j = 0; j < 8; ++j) hQ[j] = (_Float16)q8[j];
      }
      // pack px-major {A,B,P,Q | A,B,P,Q} per pair, store 4 pairs
      #pragma unroll
      for (int p = 0; p < 4; ++p) {
        h8 o = h8{hA[2*p], hB[2*p], hP[2*p], hQ[2*p],
                  hA[2*p+1], hB[2*p+1], hP[2*p+1], hQ[2*p+1]};
        *(h8*)&hb[row*HB8 + (p0 + p)*8] = o;
      }
    }
    __syncthreads();

    // ---- vertical pass: strips 2 wide x 4 rows, packed-f16 accumulate ---
    const int xp = tid & 31;          // x-pair
    const int ybase = (tid >> 5)*4;   // 0,4,..,28
    h8 vacc[4];
    #pragma unroll
    for (int m = 0; m < 4; ++m) vacc[m] = splat8((_Float16)0.f);
    #pragma unroll
    for (int r = 0; r < 14; ++r) {
      h8 rv = *(const h8*)&hb[(ybase + r)*HB8 + xp*8];
      #pragma unroll
      for (int m = 0; m < 4; ++m) {
        int k = r - m;
        if (k >= 0 && k < 11) vacc[m] += splat8(gh[k]) * rv;
      }
    }

    // ---- epilogue: SSIM for 8 px ----
    float ss = 0.f;
    #pragma unroll
    for (int m = 0; m < 4; ++m) {
      #pragma unroll
      for (int px = 0; px < 2; ++px) {
        float mu1 = (float)vacc[m][4*px + 0];
        float mu2 = (float)vacc[m][4*px + 1];
        float sP  = (float)vacc[m][4*px + 2];
        float sQ  = (float)vacc[m][4*px + 3];
        float mu12 = mu1*mu2, mss = mu1*mu1 + mu2*mu2;
        float s12 = sQ - mu12, sps = sP - mss;
        ss += ((2.f*mu12 + 1e-4f)*(2.f*s12 + 9e-4f)) /
              ((mss + 1e-4f)*(sps + 9e-4f));
      }
    }
    float tot = block_sum(ss, red);
    if (tid == 0) atomicAdd(&aslot[(pair == 3) ? 6 : 5], tot);

  } else {
    // ================= point + sobel + color block =================
    const int r = bid - 8192;
    const int x0 = (r & 7)*64;
    const int y0 = ((r >> 3) & 31)*16;
    const int n  = r >> 8;
    float* s = (float*)smem;   // 3 fields x 1224 floats (14.7 KB)
    const int ox = (tid & 15)*4;
    const int oy = tid >> 4;

    float con=0.f, gxs=0.f, gys=0.f, cbs=0.f, crs=0.f;
    float pv[3][4], pf[3][4];

    for (int c = 0; c < 3; ++c) {
      const float* pv0 = vis  + (n*3 + c)*CH_STRIDE;
      const float* pi0 = ir   + (n*3 + c)*CH_STRIDE;
      const float* pf0 = fuse + (n*3 + c)*CH_STRIDE;
      // interior: 3 fields x 18 rows x 16 f4 = 864 groups
      for (int i = tid; i < 864; i += 256) {
        int f = i / 288;
        int rr = i - f*288;
        int row = rr >> 4, k = rr & 15;
        int gy = y0 - 1 + row, gx = x0 + 4*k;
        f4 v = {0,0,0,0};
        const float* bp = (f == 0) ? pv0 : ((f == 1) ? pi0 : pf0);
        if ((unsigned)gy < IMG_H) v = *(const f4*)&bp[gy*IMG_W + gx];
        float* dst = s + f*R1N + row*R1W + 1 + 4*k;
        dst[0]=v.x; dst[1]=v.y; dst[2]=v.z; dst[3]=v.w;
      }
      // edges: 3 fields x 18 rows x 2 = 108 scalars
      if (tid < 108) {
        int f = tid / 36;
        int rr = tid - f*36;
        int row = rr >> 1, side = rr & 1;
        int gy = y0 - 1 + row;
        int gx = side ? (x0 + 64) : (x0 - 1);
        float v = 0.f;
        const float* bp = (f == 0) ? pv0 : ((f == 1) ? pi0 : pf0);
        if ((unsigned)gx < IMG_W && (unsigned)gy < IMG_H) v = bp[gy*IMG_W + gx];
        s[f*R1N + row*R1W + (side ? 65 : 0)] = v;
      }
      __syncthreads();

      float cen[3][4], gxv[3][4], gyv[3][4];
      #pragma unroll
      for (int t = 0; t < 3; ++t) {
        const float* sf = s + t*R1N;
        float r0[8], r1[8], r2[8];
        {
          f4 a = *(const f4*)&sf[(oy+0)*R1W + ox], b = *(const f4*)&sf[(oy+0)*R1W + ox + 4];
          r0[0]=a.x; r0[1]=a.y; r0[2]=a.z; r0[3]=a.w; r0[4]=b.x; r0[5]=b.y; r0[6]=b.z; r0[7]=b.w;
        }
        {
          f4 a = *(const f4*)&sf[(oy+1)*R1W + ox], b = *(const f4*)&sf[(oy+1)*R1W + ox + 4];
          r1[0]=a.x; r1[1]=a.y; r1[2]=a.z; r1[3]=a.w; r1[4]=b.x; r1[5]=b.y; r1[6]=b.z; r1[7]=b.w;
        }
        {
          f4 a = *(const f4*)&sf[(oy+2)*R1W + ox], b = *(const f4*)&sf[(oy+2)*R1W + ox + 4];
          r2[0]=a.x; r2[1]=a.y; r2[2]=a.z; r2[3]=a.w; r2[4]=b.x; r2[5]=b.y; r2[6]=b.z; r2[7]=b.w;
        }
        #pragma unroll
        for (int j = 0; j < 4; ++j) {
          gxv[t][j] = (r0[j+2]-r0[j]) + 2.f*(r1[j+2]-r1[j]) + (r2[j+2]-r2[j]);
          gyv[t][j] = (r0[j] + 2.f*r0[j+1] + r0[j+2]) - (r2[j] + 2.f*r2[j+1] + r2[j+2]);
          cen[t][j] = r1[j+1];
        }
      }
      #pragma unroll
      for (int j = 0; j < 4; ++j) {
        con += fabsf(cen[2][j] - fmaxf(cen[0][j], cen[1][j]));
        gxs += fabsf(gxv[2][j] - fmaxf(gxv[0][j], gxv[1][j]));
        gys += fabsf(gyv[2][j] - fmaxf(gyv[0][j], gyv[1][j]));
        pv[c][j] = cen[0][j];
        pf[c][j] = cen[2][j];
      }
      __syncthreads();   // WAR guard before restaging
    }

    #pragma unroll
    for (int j = 0; j < 4; ++j) {
      float Yf = 0.299f*pf[0][j] + 0.587f*pf[1][j] + 0.114f*pf[2][j];
      float Yv = 0.299f*pv[0][j] + 0.587f*pv[1][j] + 0.114f*pv[2][j];
      crs += fabsf(0.713f*((pf[0][j]-Yf) - (pv[0][j]-Yv)));
      cbs += fabsf(0.564f*((pf[2][j]-Yf) - (pv[2][j]-Yv)));
    }

    float r0 = block_sum(con, red);
    float r1 = block_sum(gxs, red);
    float r2 = block_sum(gys, red);
    float r3 = block_sum(cbs, red);
    float r4 = block_sum(crs, red);
    if (tid == 0) {
      atomicAdd(&aslot[0], r0);
      atomicAdd(&aslot[1], r1);
      atomicAdd(&aslot[2], r2);
      atomicAdd(&aslot[3], r3);
      atomicAdd(&aslot[4], r4);
    }
  }
}

// ---------------- final combine: one wave over 64 slots -------------------
__global__ __launch_bounds__(64) void k_final(
    const float* __restrict__ acc, float* __restrict__ out)
{
  int lane = threadIdx.x;
  float s[7];
  #pragma unroll
  for (int c = 0; c < 7; ++c) {
    float x = acc[lane*SLOT_F + c];
    #pragma unroll
    for (int o = 32; o > 0; o >>= 1) x += __shfl_down(x, o, 64);
    s[c] = x;
  }
  if (lane == 0) {
    const float N3 = 16.f*3.f*512.f*512.f;
    const float N1 = 16.f*512.f*512.f;
    float con_loss  = s[0] / N3;
    float grad_loss = 0.5f*(s[1]/N3) + 0.5f*(s[2]/N3);
    float color_loss = s[3]/N1 + s[4]/N1;
    float ssim_loss = 1.f - (s[5]/N3 + s[6]/N1)*0.5f;
    out[0] = 0.5f*con_loss + 0.2f*grad_loss + color_loss + 0.1f*ssim_loss;
  }
}

extern "C" void kernel_launch(void* const* d_in, const int* in_sizes, int n_in,
                              void* d_out, int out_size, void* d_ws, size_t ws_size,
                              hipStream_t stream) {
  (void)in_sizes; (void)n_in; (void)out_size; (void)ws_size;
  const float* vis  = (const float*)d_in[0];
  const float* ir   = (const float*)d_in[1];
  const float* fuse = (const float*)d_in[2];
  float* out = (float*)d_out;
  float* acc = (float*)d_ws;   // 64 slots x 32 floats = 8 KB

  k_zero<<<dim3(1,1,1), dim3(256,1,1), 0, stream>>>(acc);
  k_main<<<dim3(12288,1,1), dim3(256,1,1), 0, stream>>>(vis, ir, fuse, acc);
  k_final<<<dim3(1,1,1), dim3(64,1,1), 0, stream>>>(acc, out);
}

// Round 7
// 245.384 us; speedup vs baseline: 1.7628x; 1.0004x over previous
//
#include <hip/hip_runtime.h>

#define IMG_H 512
#define IMG_W 512
#define CH_STRIDE (IMG_H*IMG_W)     // 262144
#define IMG_STRIDE (3*CH_STRIDE)

using f4 = __attribute__((ext_vector_type(4))) float;
using h2 = __attribute__((ext_vector_type(2))) _Float16;
using h4 = __attribute__((ext_vector_type(4))) _Float16;
using h8 = __attribute__((ext_vector_type(8))) _Float16;

// acc: 64 slots x 32 floats (128 B apart):
// 0=con 1=gx 2=gy 3=cb 4=cr 5=ssim_rgb 6=ssim_ir
#define NSLOT 64
#define SLOT_F 32

__global__ __launch_bounds__(256) void k_zero(float* __restrict__ acc) {
  int i = threadIdx.x;
  *(f4*)&acc[i*8]     = f4{0,0,0,0};
  *(f4*)&acc[i*8 + 4] = f4{0,0,0,0};
}

__device__ __forceinline__ float block_sum(float v, float* red) {
  #pragma unroll
  for (int o = 32; o > 0; o >>= 1) v += __shfl_down(v, o, 64);
  __syncthreads();
  if ((threadIdx.x & 63) == 0) red[threadIdx.x >> 6] = v;
  __syncthreads();
  return red[0] + red[1] + red[2] + red[3];
}

__device__ __forceinline__ h8 splat8(_Float16 v) { return h8{v,v,v,v,v,v,v,v}; }

// ---- sobel geometry: tile 64x16, halo 1; LDS row stride 68 floats -------
#define R1W 68
#define R1N (18*R1W)   // 1224 floats per field

// ---- ssim geometry: tile 64x32, halo 5 ----------------------------------
// staged: 42 rows x 80 halves (col u <-> image x = x0-8+u)
// hbuf:   42 rows x 32 x-pairs, px-major interleave {A,B,P,Q}x2 = h8/pair
#define SXW 80
#define SXH 42
#define HB8 264                       // halves per hbuf row (32*8=256 +8 pad)
#define SSIM_SX_B (SXH*SXW*2)         // 6720
#define SSIM_HB_B (SXH*HB8*2)         // 22176
#define SMEM_BYTES (2*SSIM_SX_B + SSIM_HB_B)   // 35616 (sobel needs 14688)

__global__ __launch_bounds__(256, 4) void k_main(
    const float* __restrict__ vis, const float* __restrict__ ir,
    const float* __restrict__ fuse, float* __restrict__ acc)
{
  __shared__ __align__(16) char smem[SMEM_BYTES];
  __shared__ float red[4];
  const int tid = threadIdx.x;
  const int bid = blockIdx.x;
  float* aslot = acc + (bid & (NSLOT-1))*SLOT_F;

  if (bid < 8192) {
    // ================= SSIM block =================
    const int z = bid >> 7;             // n*4 + pair
    const int n = z >> 2, pair = z & 3;
    const int x0 = (bid & 7)*64;
    const int y0 = ((bid >> 3) & 15)*32;
    _Float16* sx = (_Float16*)smem;
    _Float16* sy = (_Float16*)(smem + SSIM_SX_B);
    _Float16* hb = (_Float16*)(smem + 2*SSIM_SX_B);

    // Gaussian weights (fp64-accurate unnormalized exp(-d^2/4.5), normalized)
    _Float16 gh[11];
    h2 gh2[11];
    {
      const float gu[6] = {0.00386592014f, 0.02856550078f, 0.13533528324f,
                           0.41111229050f, 0.80073740292f, 1.0f};
      float g[11], gs = 0.f;
      #pragma unroll
      for (int i = 0; i < 11; ++i) { g[i] = gu[i < 6 ? i : 10 - i]; gs += g[i]; }
      #pragma unroll
      for (int i = 0; i < 11; ++i) {
        g[i] /= gs;
        gh[i] = (_Float16)g[i];
        gh2[i] = h2{gh[i], gh[i]};
      }
    }

    // ---- stage (f16, zero-padded): 840 tasks = 42 rows x 20 f4-groups ---
    if (pair < 3) {
      const float* xb = vis  + (n*3 + pair)*CH_STRIDE;
      const float* yb = fuse + (n*3 + pair)*CH_STRIDE;
      for (int i = tid; i < SXH*20; i += 256) {
        int row = i / 20, k = i - row*20;
        int gy = y0 - 5 + row, gx = x0 - 8 + 4*k;
        f4 xv = {0,0,0,0}, yv = {0,0,0,0};
        if ((unsigned)gy < IMG_H && (unsigned)gx < IMG_W) {
          int off = gy*IMG_W + gx;
          xv = *(const f4*)&xb[off];
          yv = *(const f4*)&yb[off];
        }
        int ib = row*SXW + 4*k;
        *(h4*)&sx[ib] = h4{(_Float16)xv.x,(_Float16)xv.y,(_Float16)xv.z,(_Float16)xv.w};
        *(h4*)&sy[ib] = h4{(_Float16)yv.x,(_Float16)yv.y,(_Float16)yv.z,(_Float16)yv.w};
      }
    } else {
      const float* xb = ir   + n*IMG_STRIDE;
      const float* fb = fuse + n*IMG_STRIDE;
      for (int i = tid; i < SXH*20; i += 256) {
        int row = i / 20, k = i - row*20;
        int gy = y0 - 5 + row, gx = x0 - 8 + 4*k;
        f4 xv = {0,0,0,0}, yv = {0,0,0,0};
        if ((unsigned)gy < IMG_H && (unsigned)gx < IMG_W) {
          int off = gy*IMG_W + gx;
          xv = *(const f4*)&xb[off];
          f4 rr = *(const f4*)&fb[off];
          f4 gg = *(const f4*)&fb[off + CH_STRIDE];
          f4 bb = *(const f4*)&fb[off + 2*CH_STRIDE];
          #pragma unroll
          for (int j = 0; j < 4; ++j)
            yv[j] = 0.2989f*rr[j] + 0.587f*gg[j] + 0.114f*bb[j];
        }
        int ib = row*SXW + 4*k;
        *(h4*)&sx[ib] = h4{(_Float16)xv.x,(_Float16)xv.y,(_Float16)xv.z,(_Float16)xv.w};
        *(h4*)&sy[ib] = h4{(_Float16)yv.x,(_Float16)yv.y,(_Float16)yv.z,(_Float16)yv.w};
      }
    }
    __syncthreads();

    // ---- horizontal pass: 336 tasks = 42 rows x 8 x-groups --------------
    // 8 outputs/task computed as 4 packed px-pairs {j, j+4}; all f16 pk math
    for (int t = tid; t < SXH*8; t += 256) {
      int row = t >> 3, p0 = (t & 7)*4;        // pair base; x-offset = p0*2
      int base = row*SXW + p0*2;
      h8 xa0 = *(const h8*)&sx[base];
      h8 xa1 = *(const h8*)&sx[base+8];
      h8 xa2 = *(const h8*)&sx[base+16];
      h8 yb0 = *(const h8*)&sy[base];
      h8 yb1 = *(const h8*)&sy[base+8];
      h8 yb2 = *(const h8*)&sy[base+16];
      _Float16 wa[21], wb[21];
      #pragma unroll
      for (int u = 0; u < 21; ++u) {
        wa[u] = (u < 8 ? xa0[u] : (u < 16 ? xa1[u-8] : xa2[u-16]));
        wb[u] = (u < 8 ? yb0[u] : (u < 16 ? yb1[u-8] : yb2[u-16]));
      }
      // packed windows: index u covers taps for output pair {j, j+4}
      h2 pa[14], pb[14], pp[14], pq[14];
      #pragma unroll
      for (int u = 0; u < 14; ++u) {
        pa[u] = h2{wa[u+3], wa[u+7]};
        pb[u] = h2{wb[u+3], wb[u+7]};
        pp[u] = pa[u]*pa[u] + pb[u]*pb[u];
        pq[u] = pa[u]*pb[u];
      }
      h2 cA[4], cB[4], cP[4], cQ[4];
      #pragma unroll
      for (int j = 0; j < 4; ++j) { cA[j]=h2{0,0}; cB[j]=h2{0,0}; cP[j]=h2{0,0}; cQ[j]=h2{0,0}; }
      #pragma unroll
      for (int k = 0; k < 11; ++k) {
        h2 gk = gh2[k];
        #pragma unroll
        for (int j = 0; j < 4; ++j) {
          cA[j] += gk * pa[k+j];
          cB[j] += gk * pb[k+j];
          cP[j] += gk * pp[k+j];
          cQ[j] += gk * pq[k+j];
        }
      }
      // repack to px-major {A,B,P,Q|A,B,P,Q} per adjacent-px pair and store
      // px j: j<4 -> cX[j].x ; j>=4 -> cX[j-4].y
      #pragma unroll
      for (int p = 0; p < 4; ++p) {
        int j0 = 2*p, j1 = 2*p + 1;
        _Float16 a0 = (j0 < 4) ? cA[j0][0] : cA[j0-4][1];
        _Float16 b0 = (j0 < 4) ? cB[j0][0] : cB[j0-4][1];
        _Float16 P0 = (j0 < 4) ? cP[j0][0] : cP[j0-4][1];
        _Float16 q0 = (j0 < 4) ? cQ[j0][0] : cQ[j0-4][1];
        _Float16 a1 = (j1 < 4) ? cA[j1][0] : cA[j1-4][1];
        _Float16 b1 = (j1 < 4) ? cB[j1][0] : cB[j1-4][1];
        _Float16 P1 = (j1 < 4) ? cP[j1][0] : cP[j1-4][1];
        _Float16 q1 = (j1 < 4) ? cQ[j1][0] : cQ[j1-4][1];
        *(h8*)&hb[row*HB8 + (p0 + p)*8] = h8{a0,b0,P0,q0,a1,b1,P1,q1};
      }
    }
    __syncthreads();

    // ---- vertical pass: strips 2 wide x 4 rows, packed-f16 accumulate ---
    const int xp = tid & 31;          // x-pair
    const int ybase = (tid >> 5)*4;   // 0,4,..,28
    h8 vacc[4];
    #pragma unroll
    for (int m = 0; m < 4; ++m) vacc[m] = splat8((_Float16)0.f);
    #pragma unroll
    for (int r = 0; r < 14; ++r) {
      h8 rv = *(const h8*)&hb[(ybase + r)*HB8 + xp*8];
      #pragma unroll
      for (int m = 0; m < 4; ++m) {
        int k = r - m;
        if (k >= 0 && k < 11) vacc[m] += splat8(gh[k]) * rv;
      }
    }

    // ---- epilogue: SSIM for 8 px ----
    float ss = 0.f;
    #pragma unroll
    for (int m = 0; m < 4; ++m) {
      #pragma unroll
      for (int px = 0; px < 2; ++px) {
        float mu1 = (float)vacc[m][4*px + 0];
        float mu2 = (float)vacc[m][4*px + 1];
        float sP  = (float)vacc[m][4*px + 2];
        float sQ  = (float)vacc[m][4*px + 3];
        float mu12 = mu1*mu2, mss = mu1*mu1 + mu2*mu2;
        float s12 = sQ - mu12, sps = sP - mss;
        ss += ((2.f*mu12 + 1e-4f)*(2.f*s12 + 9e-4f)) /
              ((mss + 1e-4f)*(sps + 9e-4f));
      }
    }
    float tot = block_sum(ss, red);
    if (tid == 0) atomicAdd(&aslot[(pair == 3) ? 6 : 5], tot);

  } else {
    // ================= point + sobel + color block =================
    const int r = bid - 8192;
    const int x0 = (r & 7)*64;
    const int y0 = ((r >> 3) & 31)*16;
    const int n  = r >> 8;
    float* s = (float*)smem;   // 3 fields x 1224 floats (14.7 KB)
    const int ox = (tid & 15)*4;
    const int oy = tid >> 4;

    float con=0.f, gxs=0.f, gys=0.f, cbs=0.f, crs=0.f;
    float pv[3][4], pf[3][4];

    for (int c = 0; c < 3; ++c) {
      const float* pv0 = vis  + (n*3 + c)*CH_STRIDE;
      const float* pi0 = ir   + (n*3 + c)*CH_STRIDE;
      const float* pf0 = fuse + (n*3 + c)*CH_STRIDE;
      // interior: 3 fields x 18 rows x 16 f4 = 864 groups
      for (int i = tid; i < 864; i += 256) {
        int f = i / 288;
        int rr = i - f*288;
        int row = rr >> 4, k = rr & 15;
        int gy = y0 - 1 + row, gx = x0 + 4*k;
        f4 v = {0,0,0,0};
        const float* bp = (f == 0) ? pv0 : ((f == 1) ? pi0 : pf0);
        if ((unsigned)gy < IMG_H) v = *(const f4*)&bp[gy*IMG_W + gx];
        float* dst = s + f*R1N + row*R1W + 1 + 4*k;
        dst[0]=v.x; dst[1]=v.y; dst[2]=v.z; dst[3]=v.w;
      }
      // edges: 3 fields x 18 rows x 2 = 108 scalars
      if (tid < 108) {
        int f = tid / 36;
        int rr = tid - f*36;
        int row = rr >> 1, side = rr & 1;
        int gy = y0 - 1 + row;
        int gx = side ? (x0 + 64) : (x0 - 1);
        float v = 0.f;
        const float* bp = (f == 0) ? pv0 : ((f == 1) ? pi0 : pf0);
        if ((unsigned)gx < IMG_W && (unsigned)gy < IMG_H) v = bp[gy*IMG_W + gx];
        s[f*R1N + row*R1W + (side ? 65 : 0)] = v;
      }
      __syncthreads();

      float cen[3][4], gxv[3][4], gyv[3][4];
      #pragma unroll
      for (int t = 0; t < 3; ++t) {
        const float* sf = s + t*R1N;
        float r0[8], r1[8], r2[8];
        {
          f4 a = *(const f4*)&sf[(oy+0)*R1W + ox], b = *(const f4*)&sf[(oy+0)*R1W + ox + 4];
          r0[0]=a.x; r0[1]=a.y; r0[2]=a.z; r0[3]=a.w; r0[4]=b.x; r0[5]=b.y; r0[6]=b.z; r0[7]=b.w;
        }
        {
          f4 a = *(const f4*)&sf[(oy+1)*R1W + ox], b = *(const f4*)&sf[(oy+1)*R1W + ox + 4];
          r1[0]=a.x; r1[1]=a.y; r1[2]=a.z; r1[3]=a.w; r1[4]=b.x; r1[5]=b.y; r1[6]=b.z; r1[7]=b.w;
        }
        {
          f4 a = *(const f4*)&sf[(oy+2)*R1W + ox], b = *(const f4*)&sf[(oy+2)*R1W + ox + 4];
          r2[0]=a.x; r2[1]=a.y; r2[2]=a.z; r2[3]=a.w; r2[4]=b.x; r2[5]=b.y; r2[6]=b.z; r2[7]=b.w;
        }
        #pragma unroll
        for (int j = 0; j < 4; ++j) {
          gxv[t][j] = (r0[j+2]-r0[j]) + 2.f*(r1[j+2]-r1[j]) + (r2[j+2]-r2[j]);
          gyv[t][j] = (r0[j] + 2.f*r0[j+1] + r0[j+2]) - (r2[j] + 2.f*r2[j+1] + r2[j+2]);
          cen[t][j] = r1[j+1];
        }
      }
      #pragma unroll
      for (int j = 0; j < 4; ++j) {
        con += fabsf(cen[2][j] - fmaxf(cen[0][j], cen[1][j]));
        gxs += fabsf(gxv[2][j] - fmaxf(gxv[0][j], gxv[1][j]));
        gys += fabsf(gyv[2][j] - fmaxf(gyv[0][j], gyv[1][j]));
        pv[c][j] = cen[0][j];
        pf[c][j] = cen[2][j];
      }
      __syncthreads();   // WAR guard before restaging
    }

    #pragma unroll
    for (int j = 0; j < 4; ++j) {
      float Yf = 0.299f*pf[0][j] + 0.587f*pf[1][j] + 0.114f*pf[2][j];
      float Yv = 0.299f*pv[0][j] + 0.587f*pv[1][j] + 0.114f*pv[2][j];
      crs += fabsf(0.713f*((pf[0][j]-Yf) - (pv[0][j]-Yv)));
      cbs += fabsf(0.564f*((pf[2][j]-Yf) - (pv[2][j]-Yv)));
    }

    float r0 = block_sum(con, red);
    float r1 = block_sum(gxs, red);
    float r2 = block_sum(gys, red);
    float r3 = block_sum(cbs, red);
    float r4 = block_sum(crs, red);
    if (tid == 0) {
      atomicAdd(&aslot[0], r0);
      atomicAdd(&aslot[1], r1);
      atomicAdd(&aslot[2], r2);
      atomicAdd(&aslot[3], r3);
      atomicAdd(&aslot[4], r4);
    }
  }
}

// ---------------- final combine: one wave over 64 slots -------------------
__global__ __launch_bounds__(64) void k_final(
    const float* __restrict__ acc, float* __restrict__ out)
{
  int lane = threadIdx.x;
  float s[7];
  #pragma unroll
  for (int c = 0; c < 7; ++c) {
    float x = acc[lane*SLOT_F + c];
    #pragma unroll
    for (int o = 32; o > 0; o >>= 1) x += __shfl_down(x, o, 64);
    s[c] = x;
  }
  if (lane == 0) {
    const float N3 = 16.f*3.f*512.f*512.f;
    const float N1 = 16.f*512.f*512.f;
    float con_loss  = s[0] / N3;
    float grad_loss = 0.5f*(s[1]/N3) + 0.5f*(s[2]/N3);
    float color_loss = s[3]/N1 + s[4]/N1;
    float ssim_loss = 1.f - (s[5]/N3 + s[6]/N1)*0.5f;
    out[0] = 0.5f*con_loss + 0.2f*grad_loss + color_loss + 0.1f*ssim_loss;
  }
}

extern "C" void kernel_launch(void* const* d_in, const int* in_sizes, int n_in,
                              void* d_out, int out_size, void* d_ws, size_t ws_size,
                              hipStream_t stream) {
  (void)in_sizes; (void)n_in; (void)out_size; (void)ws_size;
  const float* vis  = (const float*)d_in[0];
  const float* ir   = (const float*)d_in[1];
  const float* fuse = (const float*)d_in[2];
  float* out = (float*)d_out;
  float* acc = (float*)d_ws;   // 64 slots x 32 floats = 8 KB

  k_zero<<<dim3(1,1,1), dim3(256,1,1), 0, stream>>>(acc);
  k_main<<<dim3(12288,1,1), dim3(256,1,1), 0, stream>>>(vis, ir, fuse, acc);
  k_final<<<dim3(1,1,1), dim3(64,1,1), 0, stream>>>(acc, out);
}